// Round 8
// baseline (94.096 us; speedup 1.0000x reference)
//
#include <hip/hip_runtime.h>

typedef __attribute__((ext_vector_type(8))) short          short8_t;   // 8 bf16
typedef __attribute__((ext_vector_type(8))) unsigned short ushort8_t;
typedef __attribute__((ext_vector_type(4))) float          floatx4;

constexpr int N_ROWS = 8192;
constexpr int DIM    = 64;
constexpr int PANEL  = 128 * DIM;   // 8192 ushorts = 16 KiB per (panel, hi/lo)
constexpr int STRIP  = 512;         // cols per block (4 panels in LDS)

// f32 -> bf16 round-to-nearest-even
__device__ __forceinline__ unsigned short bf16_rne(float f) {
    unsigned int u = __float_as_uint(f);
    u += 0x7FFFu + ((u >> 16) & 1u);
    return (unsigned short)(u >> 16);
}

// global(AS1) -> LDS(AS3) 16-byte async copy; LDS dest = uniform base + lane*16
typedef __attribute__((address_space(1))) unsigned int gu32;
typedef __attribute__((address_space(3))) unsigned int lu32;
__device__ __forceinline__ void gload16(const void* g, void* l) {
    __builtin_amdgcn_global_load_lds((gu32*)g, (lu32*)l, 16, 0, 0);
}

// ---------------------------------------------------------------------------
// Kernel 1: NEGATED norms + hi/lo bf16 split, written in FRAGMENT order:
//   group g of panel p, k = ks*32 + lg*8 + e:
//   ushort offset in panel-half = ((g*2 + ks)*64 + lg*16 + li)*8 + e
// so a per-(group,ks) fragment load is one contiguous 1-KiB wave load.
// ---------------------------------------------------------------------------
__global__ void __launch_bounds__(256)
split_norms_kernel(const float* __restrict__ X, const float* __restrict__ Y,
                   float* __restrict__ x2n, float* __restrict__ y2n,
                   unsigned short* __restrict__ Xs, unsigned short* __restrict__ Ys) {
    const int t  = blockIdx.x * 256 + threadIdx.x;   // [0, 16384)
    const int r  = t >> 1;                           // row
    const int h  = t & 1;                            // k-half (== ks)
    const int p  = r >> 7;
    const int rl = r & 127;
    const int g  = rl >> 4;
    const int li = rl & 15;
    const size_t pb = (size_t)p * (2 * PANEL);

    const float4* xr = reinterpret_cast<const float4*>(X + (size_t)r * DIM + h * 32);
    const float4* yr = reinterpret_cast<const float4*>(Y + (size_t)r * DIM + h * 32);

    float sx = 0.f, sy = 0.f;
#pragma unroll
    for (int c = 0; c < 4; ++c) {                    // lg = c
        const int off = ((g * 2 + h) * 64 + c * 16 + li) * 8;
        float f[8];
        ushort8_t hi, lo;

        *reinterpret_cast<float4*>(&f[0]) = xr[2 * c];
        *reinterpret_cast<float4*>(&f[4]) = xr[2 * c + 1];
#pragma unroll
        for (int e = 0; e < 8; ++e) {
            sx = fmaf(f[e], f[e], sx);
            unsigned short hh = bf16_rne(f[e]);
            hi[e] = hh;
            lo[e] = bf16_rne(f[e] - __uint_as_float((unsigned int)hh << 16));
        }
        *reinterpret_cast<ushort8_t*>(&Xs[pb + off])         = hi;
        *reinterpret_cast<ushort8_t*>(&Xs[pb + PANEL + off]) = lo;

        *reinterpret_cast<float4*>(&f[0]) = yr[2 * c];
        *reinterpret_cast<float4*>(&f[4]) = yr[2 * c + 1];
#pragma unroll
        for (int e = 0; e < 8; ++e) {
            sy = fmaf(f[e], f[e], sy);
            unsigned short hh = bf16_rne(f[e]);
            hi[e] = hh;
            lo[e] = bf16_rne(f[e] - __uint_as_float((unsigned int)hh << 16));
        }
        *reinterpret_cast<ushort8_t*>(&Ys[pb + off])         = hi;
        *reinterpret_cast<ushort8_t*>(&Ys[pb + PANEL + off]) = lo;
    }
    sx += __shfl_xor(sx, 1);
    sy += __shfl_xor(sy, 1);
    if (h == 0) { x2n[r] = -sx; y2n[r] = -sy; }      // negated norms
}

// ---------------------------------------------------------------------------
// Kernel 2: zero-global-load steady state.
// Block (256 thr, 4 waves) = 256 rows x 512 cols. The 4 Y panels for the
// strip (128 KiB hi+lo, fragment-ordered) are staged into LDS ONCE via
// global_load_lds; A-frags for each wave's 64 rows live in registers.
// Then per chunk (64 cols): 32 ds_read_b128 (linear, conflict-free) +
// 96 MFMA + exp + nt stores. No global reads, no barriers after the first:
// waves can only stall on store backpressure -> HBM write queues stay full.
// LDS 128 KiB -> 1 block/CU, 4 waves/CU (fill kernel proves that suffices).
// ---------------------------------------------------------------------------
__global__ void __launch_bounds__(256)
rbf_mfma_kernel(const unsigned short* __restrict__ Xs,
                const unsigned short* __restrict__ Ys,
                const float* __restrict__ x2n, const float* __restrict__ y2n,
                float* __restrict__ out) {
    extern __shared__ unsigned short Blds[];   // 65536 ushorts = 128 KiB

    const int tid  = threadIdx.x;
    const int lane = tid & 63;
    const int w    = tid >> 6;
    const int strip = blockIdx.x;   // 0..15  (512-col strips)
    const int band  = blockIdx.y;   // 0..31  (256-row bands)

    // ---- stage this strip's 4 Y panels (hi+lo) -> LDS, linear copy ----
    {
        const unsigned short* src = Ys + (size_t)strip * (8 * PANEL);  // 4 x 2*PANEL
#pragma unroll
        for (int it = 0; it < 32; ++it) {
            const int ofs = ((w * 32 + it) * 64 + lane) * 8;   // 16 B per lane
            gload16(src + ofs, Blds + ofs);
        }
    }

    // ---- A fragments for this wave's 64 rows (registers, once) ----
    const int row0 = band * 256 + w * 64;
    short8_t aH[4][2], aL[4][2];
    {
        const int gx0 = row0 >> 4;
#pragma unroll
        for (int gx = 0; gx < 4; ++gx) {
            const int gabs = gx0 + gx;
            const unsigned short* base = Xs + (size_t)(gabs >> 3) * (2 * PANEL);
            const int g = gabs & 7;
#pragma unroll
            for (int ks = 0; ks < 2; ++ks) {
                const int off = ((g * 2 + ks) * 64 + lane) * 8;
                aH[gx][ks] = *reinterpret_cast<const short8_t*>(base + off);
                aL[gx][ks] = *reinterpret_cast<const short8_t*>(base + PANEL + off);
            }
        }
    }
    __syncthreads();   // drains vmcnt (gload_lds) + lgkm before LDS reads

    const int li = lane & 15;
    const int lg = lane >> 4;

    for (int ch = 0; ch < 8; ++ch) {
        // ---- B fragments from LDS (linear 1-KiB reads, conflict-free) ----
        short8_t bH[4][2], bL[4][2];
#pragma unroll
        for (int ni = 0; ni < 4; ++ni) {
            const int gy = ch * 4 + ni;           // col group within strip
            const unsigned short* p =
                Blds + (gy >> 3) * (2 * PANEL);
            const int g = gy & 7;
#pragma unroll
            for (int ks = 0; ks < 2; ++ks) {
                const int off = ((g * 2 + ks) * 64 + lane) * 8;
                bH[ni][ks] = *reinterpret_cast<const short8_t*>(p + off);
                bL[ni][ks] = *reinterpret_cast<const short8_t*>(p + PANEL + off);
            }
        }

        // ---- 96 MFMA: Xh.Yh + Xh.Yl + Xl.Yh ----
        floatx4 acc[4][4] = {};
#pragma unroll
        for (int ks = 0; ks < 2; ++ks) {
#pragma unroll
            for (int mi = 0; mi < 4; ++mi)
#pragma unroll
                for (int ni = 0; ni < 4; ++ni)
                    acc[mi][ni] = __builtin_amdgcn_mfma_f32_16x16x32_bf16(
                        bH[ni][ks], aH[mi][ks], acc[mi][ni], 0, 0, 0);
#pragma unroll
            for (int mi = 0; mi < 4; ++mi)
#pragma unroll
                for (int ni = 0; ni < 4; ++ni)
                    acc[mi][ni] = __builtin_amdgcn_mfma_f32_16x16x32_bf16(
                        bL[ni][ks], aH[mi][ks], acc[mi][ni], 0, 0, 0);
#pragma unroll
            for (int mi = 0; mi < 4; ++mi)
#pragma unroll
                for (int ni = 0; ni < 4; ++ni)
                    acc[mi][ni] = __builtin_amdgcn_mfma_f32_16x16x32_bf16(
                        bH[ni][ks], aL[mi][ks], acc[mi][ni], 0, 0, 0);
        }

        // ---- epilogue: exp(min(2*xy + (-x2) + (-y2), 0)), nt stores ----
        const int ocol = strip * STRIP + ch * 64 + lg * 4;
#pragma unroll
        for (int mi = 0; mi < 4; ++mi) {
            const int rbase = row0 + mi * 16 + li;
            const float xs = x2n[rbase];
            float* obase = out + (size_t)rbase * N_ROWS + ocol;
#pragma unroll
            for (int ni = 0; ni < 4; ++ni) {
                const float4 yv = *reinterpret_cast<const float4*>(&y2n[ocol + ni * 16]);
                floatx4 o;
                o[0] = __expf(fminf(fmaf(2.f, acc[mi][ni][0], xs + yv.x), 0.f));
                o[1] = __expf(fminf(fmaf(2.f, acc[mi][ni][1], xs + yv.y), 0.f));
                o[2] = __expf(fminf(fmaf(2.f, acc[mi][ni][2], xs + yv.z), 0.f));
                o[3] = __expf(fminf(fmaf(2.f, acc[mi][ni][3], xs + yv.w), 0.f));
                __builtin_nontemporal_store(o, reinterpret_cast<floatx4*>(obase + ni * 16));
            }
        }
    }
}

// ---------------------------------------------------------------------------
extern "C" void kernel_launch(void* const* d_in, const int* in_sizes, int n_in,
                              void* d_out, int out_size, void* d_ws, size_t ws_size,
                              hipStream_t stream) {
    const float* X = (const float*)d_in[0];
    const float* Y = (const float*)d_in[1];
    float* out = (float*)d_out;

    float* x2n = (float*)d_ws;                             // 8192 f32 (negated)
    float* y2n = x2n + N_ROWS;                             // 8192 f32 (negated)
    unsigned short* Xs = (unsigned short*)(y2n + N_ROWS);  // 2 MiB
    unsigned short* Ys = Xs + (N_ROWS / 128) * 2 * PANEL;  // 2 MiB

    split_norms_kernel<<<(2 * N_ROWS) / 256, 256, 0, stream>>>(X, Y, x2n, y2n, Xs, Ys);

    dim3 grid(N_ROWS / STRIP, N_ROWS / 256);   // 16 x 32 = 512 blocks
    rbf_mfma_kernel<<<grid, 256, 131072, stream>>>(Xs, Ys, x2n, y2n, out);
}